// Round 1
// baseline (171.178 us; speedup 1.0000x reference)
//
#include <hip/hip_runtime.h>
#include <hip/hip_fp16.h>
#include <stdint.h>

// Problem: out[16384,1024] = fp16(x)[16384,1024] @ fp16(sparsify24(fp16(W))*scale)[1024,1024] + bias
#define M_TOT 16384
#define N_TOT 1024
#define K_TOT 1024

typedef _Float16 f16x8 __attribute__((ext_vector_type(8)));
typedef float f32x4 __attribute__((ext_vector_type(4)));

// async global->LDS DMA, 16B per lane. LDS dest must be wave-uniform base + lane*16.
__device__ inline void gl2lds16(const void* g, void* l) {
    __builtin_amdgcn_global_load_lds(
        (const __attribute__((address_space(1))) void*)(uintptr_t)(g),
        (__attribute__((address_space(3))) void*)(uint32_t)(uintptr_t)(l),
        16, 0, 0);
}

// --- Kernel 1: W[K][N] fp32 -> 2:4 sparsify (fp16 domain) * scale -> wT[N][K] fp16 ---
__global__ void prep_weight(const float* __restrict__ W,
                            const float* __restrict__ scale_p,
                            _Float16* __restrict__ wT) {
    const float scale = scale_p[0];
    int idx = blockIdx.x * blockDim.x + threadIdx.x;   // K*N/4 = 262144 threads
    int k = idx & (K_TOT - 1);                         // k fastest -> coalesced wT writes
    int g = idx >> 10;                                 // group along N, 0..255
    float4 w4 = *(const float4*)&W[(size_t)k * N_TOT + g * 4];
    _Float16 h0 = (_Float16)w4.x, h1 = (_Float16)w4.y, h2 = (_Float16)w4.z, h3 = (_Float16)w4.w;
    float a0 = fabsf((float)h0), a1 = fabsf((float)h1), a2 = fabsf((float)h2), a3 = fabsf((float)h3);
    // 2nd-largest of 4 (== sorted-ascending index 2), exact tie semantics: keep a >= s2
    float lo01 = fminf(a0, a1), hi01 = fmaxf(a0, a1);
    float lo23 = fminf(a2, a3), hi23 = fmaxf(a2, a3);
    float s2 = fmaxf(fminf(hi01, hi23), fmaxf(lo01, lo23));
    float v0 = (a0 >= s2) ? (float)h0 : 0.0f;
    float v1 = (a1 >= s2) ? (float)h1 : 0.0f;
    float v2 = (a2 >= s2) ? (float)h2 : 0.0f;
    float v3 = (a3 >= s2) ? (float)h3 : 0.0f;
    size_t nb = (size_t)(g * 4) * K_TOT + k;
    wT[nb + 0 * K_TOT] = (_Float16)(v0 * scale);
    wT[nb + 1 * K_TOT] = (_Float16)(v1 * scale);
    wT[nb + 2 * K_TOT] = (_Float16)(v2 * scale);
    wT[nb + 3 * K_TOT] = (_Float16)(v3 * scale);
}

// --- Kernel 2: x fp32 -> fp16 ---
__global__ void cast_x(const float* __restrict__ X, _Float16* __restrict__ Xh) {
    size_t i = ((size_t)blockIdx.x * blockDim.x + threadIdx.x) * 8;
    float4 x0 = *(const float4*)&X[i];
    float4 x1 = *(const float4*)&X[i + 4];
    f16x8 h;
    h[0] = (_Float16)x0.x; h[1] = (_Float16)x0.y; h[2] = (_Float16)x0.z; h[3] = (_Float16)x0.w;
    h[4] = (_Float16)x1.x; h[5] = (_Float16)x1.y; h[6] = (_Float16)x1.z; h[7] = (_Float16)x1.w;
    *(f16x8*)&Xh[i] = h;
}

// --- Kernel 3: C = A[M][K] * wT[N][K]^T + bias, m97-style 128x128 tile, BK=32 ---
__global__ void __launch_bounds__(256) gemm_bt(const _Float16* __restrict__ A,
                                               const _Float16* __restrict__ Bt,
                                               const float* __restrict__ bias,
                                               float* __restrict__ C) {
    __shared__ _Float16 sA[128 * 32];
    __shared__ _Float16 sB[128 * 32];
    const int tid = threadIdx.x;
    const int bx = blockIdx.x;          // N tile: 0..7
    const int by = blockIdx.y;          // M tile: 0..127
    const int wave = tid >> 6;
    const int lane = tid & 63;
    const int wm = wave >> 1, wn = wave & 1;
    const int quad = lane >> 4;
    const int l16 = lane & 15;

    const int srow = tid >> 2;          // 0..63
    const int scol = (tid & 3) * 8;     // 0,8,16,24

    const _Float16* gA = A + ((size_t)(by * 128 + srow)) * K_TOT + scol;
    const _Float16* gB = Bt + ((size_t)(bx * 128 + srow)) * K_TOT + scol;
    _Float16* lA = sA + srow * 32 + scol;   // byte offset == tid*16 (lane-contiguous)
    _Float16* lB = sB + srow * 32 + scol;

    f32x4 acc[4][4];
#pragma unroll
    for (int i = 0; i < 4; ++i)
#pragma unroll
        for (int j = 0; j < 4; ++j)
            acc[i][j] = (f32x4){0.f, 0.f, 0.f, 0.f};

    for (int k0 = 0; k0 < K_TOT; k0 += 32) {
        __syncthreads();                 // prior iter's ds_reads complete
        gl2lds16(gA + k0, lA);
        gl2lds16(gA + k0 + (size_t)64 * K_TOT, lA + 64 * 32);
        gl2lds16(gB + k0, lB);
        gl2lds16(gB + k0 + (size_t)64 * K_TOT, lB + 64 * 32);
        __syncthreads();                 // compiler drains vmcnt(0) before s_barrier

        f16x8 af[4], bf[4];
#pragma unroll
        for (int i = 0; i < 4; ++i) {
            af[i] = *(const f16x8*)&sA[(wm * 64 + i * 16 + l16) * 32 + quad * 8];
            bf[i] = *(const f16x8*)&sB[(wn * 64 + i * 16 + l16) * 32 + quad * 8];
        }
#pragma unroll
        for (int i = 0; i < 4; ++i)
#pragma unroll
            for (int j = 0; j < 4; ++j)
                acc[i][j] = __builtin_amdgcn_mfma_f32_16x16x32_f16(af[i], bf[j], acc[i][j], 0, 0, 0);
    }

    // epilogue: D row = quad*4 + r, col = l16 (per 16x16 tile); add bias, fp32 store
#pragma unroll
    for (int j = 0; j < 4; ++j) {
        const int col = bx * 128 + wn * 64 + j * 16 + l16;
        const float bj = bias[col];
#pragma unroll
        for (int i = 0; i < 4; ++i) {
            const int row0 = by * 128 + wm * 64 + i * 16 + quad * 4;
#pragma unroll
            for (int r = 0; r < 4; ++r) {
                C[(size_t)(row0 + r) * N_TOT + col] = acc[i][j][r] + bj;
            }
        }
    }
}

extern "C" void kernel_launch(void* const* d_in, const int* in_sizes, int n_in,
                              void* d_out, int out_size, void* d_ws, size_t ws_size,
                              hipStream_t stream) {
    const float* x      = (const float*)d_in[0];   // [4,4096,1024] fp32
    const float* weight = (const float*)d_in[1];   // [1024,1024] fp32
    const float* bias   = (const float*)d_in[2];   // [1024] fp32
    const float* sscale = (const float*)d_in[3];   // [1] fp32
    float* out = (float*)d_out;

    _Float16* wT = (_Float16*)d_ws;                                   // 2 MiB
    _Float16* xh = (_Float16*)((char*)d_ws + (size_t)2 * 1024 * 1024); // 32 MiB

    prep_weight<<<(K_TOT * N_TOT / 4) / 256, 256, 0, stream>>>(weight, sscale, wT);
    cast_x<<<(M_TOT * K_TOT / 8) / 256, 256, 0, stream>>>(x, xh);
    dim3 grid(N_TOT / 128, M_TOT / 128);
    gemm_bt<<<grid, 256, 0, stream>>>(xh, wT, bias, out);
}